// Round 7
// baseline (9988.443 us; speedup 1.0000x reference)
//
#include <hip/hip_runtime.h>
#include <hip/hip_bf16.h>
#include <cstdint>
#include <cstddef>

#define N_NODES 50000
#define DIM 512
#define N_EDGES 1600000
#define NT 25            // column tiles of 2048 nodes (2 MB of bf16 y per tile)
#define SWEEP_WAVES 4096 // 1024 blocks * 4 waves, exactly co-resident at 4 blk/CU
#define RPW 13           // rows per wave: r = w + (k<<12), k in [0,13)
#define NB2 (NT * SWEEP_WAVES * RPW)   // 1,331,200 buckets

typedef __bf16 bf16;
typedef __bf16 bf16x8 __attribute__((ext_vector_type(8)));
typedef __bf16 bf16x4 __attribute__((ext_vector_type(4)));
typedef float floatx4 __attribute__((ext_vector_type(4)));

// ---------------- cast fp32 -> bf16 (4 elems / thread) ----------------
__global__ void cast_kernel(const float* __restrict__ in, bf16* __restrict__ out, int n4) {
    int i = blockIdx.x * blockDim.x + threadIdx.x;
    if (i >= n4) return;
    float4 v = reinterpret_cast<const float4*>(in)[i];
    bf16x4 o;
    o[0] = (bf16)v.x; o[1] = (bf16)v.y; o[2] = (bf16)v.z; o[3] = (bf16)v.w;
    reinterpret_cast<bf16x4*>(out)[i] = o;
}

// ---------------- bucketed CSR build ----------------
// key = (t*4096 + w)*13 + k  with w = r & 4095, k = r >> 12, t = col >> 11.
// => a wave's 13 rows at tile t form ONE contiguous edge segment (superseg):
//    [row_start[(t*4096+w)*13], row_start[(t*4096+w)*13 + 13])
// k is packed into bits 16..19 of ecv.x (col < 50000 fits in 16 bits).
__global__ void hist_kernel(const int* __restrict__ rows, const int* __restrict__ cols,
                            int* __restrict__ cnt, int E) {
    int i = blockIdx.x * blockDim.x + threadIdx.x;
    if (i < E) {
        int r = rows[i];
        int key = ((cols[i] >> 11) * 4096 + (r & 4095)) * 13 + (r >> 12);
        atomicAdd(&cnt[key], 1);
    }
}

// hierarchical scan over NB2 buckets
__global__ __launch_bounds__(1024) void scanA_kernel(const int* __restrict__ cnt,
                                                     int* __restrict__ row_start,
                                                     int* __restrict__ blksum, int n) {
    __shared__ int s[1024];
    const int t = threadIdx.x;
    int i = blockIdx.x * 1024 + t;
    int v = (i < n) ? cnt[i] : 0;
    s[t] = v;
    __syncthreads();
    for (int off = 1; off < 1024; off <<= 1) {
        int u = (t >= off) ? s[t - off] : 0;
        __syncthreads();
        s[t] += u;
        __syncthreads();
    }
    if (i < n) row_start[i] = s[t] - v;  // exclusive within block
    if (t == 1023) blksum[blockIdx.x] = s[1023];
}

__global__ __launch_bounds__(1024) void scanB_kernel(const int* __restrict__ blksum,
                                                     int* __restrict__ blkoff, int nb) {
    __shared__ int s[1024];
    const int t = threadIdx.x;
    const int base = t * 2;
    int a = (base < nb) ? blksum[base] : 0;
    int b = (base + 1 < nb) ? blksum[base + 1] : 0;
    s[t] = a + b;
    __syncthreads();
    for (int off = 1; off < 1024; off <<= 1) {
        int u = (t >= off) ? s[t - off] : 0;
        __syncthreads();
        s[t] += u;
        __syncthreads();
    }
    int excl = (t == 0) ? 0 : s[t - 1];
    if (base < nb) blkoff[base] = excl;
    if (base + 1 < nb) blkoff[base + 1] = excl + a;
}

__global__ __launch_bounds__(1024) void scanC_kernel(int* __restrict__ row_start,
                                                     const int* __restrict__ blkoff,
                                                     int* __restrict__ cursor, int n) {
    int i = blockIdx.x * 1024 + threadIdx.x;
    if (i >= n) return;
    int v = row_start[i] + blkoff[i >> 10];
    row_start[i] = v;
    cursor[i] = v;
    if (i == n - 1) row_start[n] = N_EDGES;
}

__global__ void scatter_kernel(const int* __restrict__ rows, const int* __restrict__ cols,
                               const float* __restrict__ vals, int* __restrict__ cursor,
                               int2* __restrict__ ecv, int E) {
    int i = blockIdx.x * blockDim.x + threadIdx.x;
    if (i >= E) return;
    int r = rows[i];
    int c = cols[i];
    int k = r >> 12;
    int key = ((c >> 11) * 4096 + (r & 4095)) * 13 + k;
    int p = atomicAdd(&cursor[key], 1);
    ecv[p] = make_int2(c | (k << 16), __float_as_int(vals[i]));
}

// ---------------- GEMM: y[M][512] = xb[M][512] @ Wb[512][512]^T (bf16 in, bf16 out) ----
__global__ __launch_bounds__(256) void gemm_kernel(const bf16* __restrict__ A,
                                                   const bf16* __restrict__ B,
                                                   bf16* __restrict__ C) {
    __shared__ bf16 lA[128 * 32];
    __shared__ bf16 lB[128 * 32];
    const int t = threadIdx.x;
    const int wave = t >> 6;
    const int lane = t & 63;
    const int rowBase = blockIdx.x * 128;
    const int colBase = blockIdx.y * 128;
    const int wm = (wave >> 1) * 64;
    const int wn = (wave & 1) * 64;
    floatx4 acc[4][4] = {};

    const int r_a = t >> 2;       // 0..63 (tile row, first half)
    const int kk = (t & 3) * 8;   // k offset within 32-chunk

    const int l15 = lane & 15;
    const int koff = (lane >> 4) * 8;

    for (int k0 = 0; k0 < DIM; k0 += 32) {
#pragma unroll
        for (int j = 0; j < 2; j++) {
            int row = rowBase + r_a + j * 64;
            if (row > N_NODES - 1) row = N_NODES - 1;  // clamp OOB loads (stores guarded)
            const bf16* g = A + (size_t)row * DIM + k0 + kk;
            bf16* l = lA + wave * 512 + j * 2048;  // wave-uniform base; HW adds lane*16B
            __builtin_amdgcn_global_load_lds(
                (const __attribute__((address_space(1))) void*)g,
                (__attribute__((address_space(3))) void*)l, 16, 0, 0);
        }
#pragma unroll
        for (int j = 0; j < 2; j++) {
            int row = colBase + r_a + j * 64;  // always < 512
            const bf16* g = B + (size_t)row * DIM + k0 + kk;
            bf16* l = lB + wave * 512 + j * 2048;
            __builtin_amdgcn_global_load_lds(
                (const __attribute__((address_space(1))) void*)g,
                (__attribute__((address_space(3))) void*)l, 16, 0, 0);
        }
        __syncthreads();
        bf16x8 af[4], bfr[4];
#pragma unroll
        for (int i = 0; i < 4; i++)
            af[i] = *reinterpret_cast<const bf16x8*>(lA + (wm + i * 16 + l15) * 32 + koff);
#pragma unroll
        for (int j = 0; j < 4; j++)
            bfr[j] = *reinterpret_cast<const bf16x8*>(lB + (wn + j * 16 + l15) * 32 + koff);
#pragma unroll
        for (int i = 0; i < 4; i++)
#pragma unroll
            for (int j = 0; j < 4; j++)
                acc[i][j] = __builtin_amdgcn_mfma_f32_16x16x32_bf16(af[i], bfr[j], acc[i][j], 0, 0, 0);
        __syncthreads();
    }
    // epilogue: D row = (lane>>4)*4+reg (m), col = lane&15 (n)
    const int rquad = (lane >> 4) * 4;
#pragma unroll
    for (int i = 0; i < 4; i++) {
#pragma unroll
        for (int reg = 0; reg < 4; reg++) {
            int gr = rowBase + wm + i * 16 + rquad + reg;
            if (gr >= N_NODES) continue;
#pragma unroll
            for (int j = 0; j < 4; j++) {
                int gc = colBase + wn + j * 16 + l15;
                C[(size_t)gr * DIM + gc] = (bf16)acc[i][j][reg];
            }
        }
    }
}

// ---------------- SpMM v6: co-resident tile sweep + contiguous supersegs ----------------
// v5 proved the locality (FETCH 793->469 MB, near the 410 MB floor) but its per-bucket
// serial chain (bounds->desc->gather per ~1.3 edges, 325 buckets/wave) made it
// latency-bound (1.5 TB/s). v6 keys the CSR so a wave's 13 rows at tile t are ONE
// contiguous ~17-edge segment: 2 bound loads per tile, then v4-style batched desc
// loads + 4 gathers in flight. Row index k is packed in desc bits 16..19; it is
// wave-uniform per edge, so readfirstlane + a 13-case scalar switch routes the fmac
// into statically-indexed acc[k] (no runtime register indexing -> no scratch).
__device__ __forceinline__ float blo(uint32_t w) { return __uint_as_float(w << 16); }
__device__ __forceinline__ float bhi(uint32_t w) { return __uint_as_float(w & 0xffff0000u); }

__device__ __forceinline__ void fmac8(float* acc, float v, const uint4& w) {
    acc[0] += v * blo(w.x); acc[1] += v * bhi(w.x);
    acc[2] += v * blo(w.y); acc[3] += v * bhi(w.y);
    acc[4] += v * blo(w.z); acc[5] += v * bhi(w.z);
    acc[6] += v * blo(w.w); acc[7] += v * bhi(w.w);
}

__device__ __forceinline__ uint4 grow(const uint32_t* yb, int col, int laneo) {
    return *reinterpret_cast<const uint4*>(yb + (size_t)col * 256 + laneo);
}

// route fmac by wave-uniform k (scalar switch; acc indices all compile-time constant)
#define FMACK(kx, vv, g)                                              \
    do {                                                              \
        const int k_ = __builtin_amdgcn_readfirstlane((kx)) >> 16;    \
        const float v_ = __int_as_float((vv));                        \
        switch (k_) {                                                 \
            case 0:  fmac8(acc[0],  v_, (g)); break;                  \
            case 1:  fmac8(acc[1],  v_, (g)); break;                  \
            case 2:  fmac8(acc[2],  v_, (g)); break;                  \
            case 3:  fmac8(acc[3],  v_, (g)); break;                  \
            case 4:  fmac8(acc[4],  v_, (g)); break;                  \
            case 5:  fmac8(acc[5],  v_, (g)); break;                  \
            case 6:  fmac8(acc[6],  v_, (g)); break;                  \
            case 7:  fmac8(acc[7],  v_, (g)); break;                  \
            case 8:  fmac8(acc[8],  v_, (g)); break;                  \
            case 9:  fmac8(acc[9],  v_, (g)); break;                  \
            case 10: fmac8(acc[10], v_, (g)); break;                  \
            case 11: fmac8(acc[11], v_, (g)); break;                  \
            default: fmac8(acc[12], v_, (g)); break;                  \
        }                                                             \
    } while (0)

__global__ __launch_bounds__(256, 4) void spmm_kernel(const int* __restrict__ row_start,
                                                      const int2* __restrict__ ecv,
                                                      const bf16* __restrict__ y,
                                                      float* __restrict__ y2) {
    const int wid = (blockIdx.x << 2) + (threadIdx.x >> 6);  // 0..4095
    const int lane = threadIdx.x & 63;
    const uint32_t* yb = reinterpret_cast<const uint32_t*>(y);
    const int laneo = lane * 4;  // uint32 offset within a 1KB y-row

    float acc[RPW][8];
#pragma unroll
    for (int k = 0; k < RPW; k++)
#pragma unroll
        for (int j = 0; j < 8; j++) acc[k][j] = 0.f;

    for (int t = 0; t < NT; t++) {
        const int base = (t * SWEEP_WAVES + wid) * RPW;
        int i = row_start[base];
        const int e = row_start[base + RPW];

        // peel to even index so int4 descriptor loads are 16B-aligned
        if ((i & 1) && i < e) {
            int2 ed = ecv[i];
            uint4 w0 = grow(yb, ed.x & 0xFFFF, laneo);
            FMACK(ed.x, ed.y, w0);
            i++;
        }
        // 4-edge batches: 2 independent int4 desc loads, 4 gathers in flight
        for (; i + 4 <= e; i += 4) {
            int4 d0 = *reinterpret_cast<const int4*>(ecv + i);
            int4 d1 = *reinterpret_cast<const int4*>(ecv + i + 2);
            uint4 g0 = grow(yb, d0.x & 0xFFFF, laneo);
            uint4 g1 = grow(yb, d0.z & 0xFFFF, laneo);
            uint4 g2 = grow(yb, d1.x & 0xFFFF, laneo);
            uint4 g3 = grow(yb, d1.z & 0xFFFF, laneo);
            FMACK(d0.x, d0.y, g0);
            FMACK(d0.z, d0.w, g1);
            FMACK(d1.x, d1.y, g2);
            FMACK(d1.z, d1.w, g3);
        }
        for (; i + 2 <= e; i += 2) {
            int4 d0 = *reinterpret_cast<const int4*>(ecv + i);
            uint4 g0 = grow(yb, d0.x & 0xFFFF, laneo);
            uint4 g1 = grow(yb, d0.z & 0xFFFF, laneo);
            FMACK(d0.x, d0.y, g0);
            FMACK(d0.z, d0.w, g1);
        }
        if (i < e) {
            int2 ed = ecv[i];
            uint4 w0 = grow(yb, ed.x & 0xFFFF, laneo);
            FMACK(ed.x, ed.y, w0);
        }
    }

#pragma unroll
    for (int k = 0; k < RPW; k++) {
        const int r = wid + (k << 12);
        if (r < N_NODES) {
            float4* out = reinterpret_cast<float4*>(y2 + (size_t)r * DIM + lane * 8);
            out[0] = make_float4(acc[k][0], acc[k][1], acc[k][2], acc[k][3]);
            out[1] = make_float4(acc[k][4], acc[k][5], acc[k][6], acc[k][7]);
        }
    }
}

// ---------------- reduction: colsum[512] + total sum of squares ----------------
#define RED_GRID 512
__global__ __launch_bounds__(256) void reduce_kernel(const float* __restrict__ y2,
                                                     float* __restrict__ colsum,
                                                     float* __restrict__ totsq) {
    const int t = threadIdx.x;
    const int d2 = t * 2;
    float c0 = 0.f, c1 = 0.f, sq = 0.f;
    for (int r = blockIdx.x; r < N_NODES; r += RED_GRID * 2) {
        float2 v = *reinterpret_cast<const float2*>(y2 + (size_t)r * DIM + d2);
        int r2 = r + RED_GRID;
        float2 u = (r2 < N_NODES)
                       ? *reinterpret_cast<const float2*>(y2 + (size_t)r2 * DIM + d2)
                       : make_float2(0.f, 0.f);
        c0 += v.x + u.x;
        c1 += v.y + u.y;
        sq += v.x * v.x + v.y * v.y + u.x * u.x + u.y * u.y;
    }
    atomicAdd(&colsum[d2], c0);
    atomicAdd(&colsum[d2 + 1], c1);
    __shared__ float ssq[256];
    ssq[t] = sq;
    __syncthreads();
    for (int off = 128; off > 0; off >>= 1) {
        if (t < off) ssq[t] += ssq[t + off];
        __syncthreads();
    }
    if (t == 0) atomicAdd(totsq, ssq[0]);
}

__global__ void scalar_kernel(const float* __restrict__ colsum, const float* __restrict__ totsq,
                              const float* __restrict__ scale, float* __restrict__ sfac) {
    __shared__ float sm[512];
    const int t = threadIdx.x;
    float mu = colsum[t] * (1.0f / N_NODES);
    sm[t] = mu * mu;
    __syncthreads();
    for (int off = 256; off > 0; off >>= 1) {
        if (t < off) sm[t] += sm[t + off];
        __syncthreads();
    }
    if (t == 0) {
        float var = totsq[0] * (1.0f / N_NODES) - sm[0];
        sfac[0] = rsqrtf(var) * (1.0f + scale[0]) * sqrtf((float)DIM);
    }
}

// ---------------- final: out = relu((y2 - mu) * s) + x  (in place on d_out) ----------------
__global__ void final_kernel(float* __restrict__ y2, const float* __restrict__ x,
                             const float* __restrict__ colsum, const float* __restrict__ sfac,
                             int n4) {
    int i = blockIdx.x * blockDim.x + threadIdx.x;
    if (i >= n4) return;
    const float invN = 1.0f / N_NODES;
    float4 v = reinterpret_cast<float4*>(y2)[i];
    float4 xv = reinterpret_cast<const float4*>(x)[i];
    float4 mu = reinterpret_cast<const float4*>(colsum)[i & 127];
    float s = sfac[0];
    v.x = fmaxf((v.x - mu.x * invN) * s, 0.0f) + xv.x;
    v.y = fmaxf((v.y - mu.y * invN) * s, 0.0f) + xv.y;
    v.z = fmaxf((v.z - mu.z * invN) * s, 0.0f) + xv.z;
    v.w = fmaxf((v.w - mu.w * invN) * s, 0.0f) + xv.w;
    reinterpret_cast<float4*>(y2)[i] = v;
}

extern "C" void kernel_launch(void* const* d_in, const int* in_sizes, int n_in,
                              void* d_out, int out_size, void* d_ws, size_t ws_size,
                              hipStream_t stream) {
    const float* x        = (const float*)d_in[0];
    const int*   adj_rows = (const int*)d_in[1];
    const int*   adj_cols = (const int*)d_in[2];
    const float* adj_vals = (const float*)d_in[3];
    const float* weight   = (const float*)d_in[4];
    const float* scale    = (const float*)d_in[5];
    float* out = (float*)d_out;  // doubles as y2 buffer

    char* ws = (char*)d_ws;
    size_t off = 0;
    auto alloc = [&](size_t b) {
        char* p = ws + off;
        off += (b + 255) & ~(size_t)255;
        return p;
    };
    const int nblk = (NB2 + 1023) / 1024;  // 1300
    bf16*  xb        = (bf16*)alloc((size_t)N_NODES * DIM * 2);   // 51.2 MB
    int2*  ecv       = (int2*)xb;  // ALIAS: gemm (reader of xb) completes before scatter writes
    bf16*  Wb        = (bf16*)alloc((size_t)DIM * DIM * 2);       // 0.5 MB
    bf16*  y         = (bf16*)alloc((size_t)N_NODES * DIM * 2);   // 51.2 MB
    int*   cnt       = (int*)alloc((size_t)NB2 * 4);              // 5.3 MB
    int*   cursor    = cnt;        // ALIAS: cnt dead after scanA; cursor born in scanC
    int*   row_start = (int*)alloc((size_t)(NB2 + 32) * 4);       // 5.3 MB (+pad)
    int*   blksum    = (int*)alloc((size_t)nblk * 4);
    int*   blkoff    = (int*)alloc((size_t)nblk * 4);
    float* colsum    = (float*)alloc(512 * 4);
    float* totsq     = (float*)alloc(4);
    float* sfac      = (float*)alloc(4);
    (void)ws_size; (void)in_sizes; (void)n_in; (void)out_size;

    hipMemsetAsync(cnt, 0, (size_t)NB2 * 4, stream);
    hipMemsetAsync(colsum, 0, 512 * 4, stream);
    hipMemsetAsync(totsq, 0, 4, stream);

    const int n4x = N_NODES * DIM / 4;  // 6,400,000
    const int n4w = DIM * DIM / 4;      // 65,536
    cast_kernel<<<(n4x + 255) / 256, 256, 0, stream>>>(x, xb, n4x);
    cast_kernel<<<(n4w + 255) / 256, 256, 0, stream>>>(weight, Wb, n4w);

    // GEMM first: frees xb so ecv can alias it
    gemm_kernel<<<dim3((N_NODES + 127) / 128, DIM / 128), 256, 0, stream>>>(xb, Wb, y);

    hist_kernel<<<(N_EDGES + 255) / 256, 256, 0, stream>>>(adj_rows, adj_cols, cnt, N_EDGES);
    scanA_kernel<<<nblk, 1024, 0, stream>>>(cnt, row_start, blksum, NB2);
    scanB_kernel<<<1, 1024, 0, stream>>>(blksum, blkoff, nblk);
    scanC_kernel<<<nblk, 1024, 0, stream>>>(row_start, blkoff, cursor, NB2);
    scatter_kernel<<<(N_EDGES + 255) / 256, 256, 0, stream>>>(adj_rows, adj_cols, adj_vals,
                                                              cursor, ecv, N_EDGES);

    // persistent tile-synchronized sweep: 1024 blocks = 4/CU, all co-resident
    spmm_kernel<<<1024, 256, 0, stream>>>(row_start, ecv, y, out);

    reduce_kernel<<<RED_GRID, 256, 0, stream>>>(out, colsum, totsq);
    scalar_kernel<<<1, 512, 0, stream>>>(colsum, totsq, scale, sfac);
    final_kernel<<<(n4x + 255) / 256, 256, 0, stream>>>(out, x, colsum, sfac, n4x);
}

// Round 8
// 915.014 us; speedup vs baseline: 10.9162x; 10.9162x over previous
//
#include <hip/hip_runtime.h>
#include <hip/hip_bf16.h>
#include <cstdint>
#include <cstddef>

#define N_NODES 50000
#define DIM 512
#define N_EDGES 1600000
#define NT 25            // column tiles of 2048 nodes (2 MB of bf16 y per tile)
#define SWEEP_WAVES 4096 // 1024 blocks * 4 waves
#define RPW 13           // rows per wave: r = w + (k<<12), k in [0,13)
#define NB2 (NT * SWEEP_WAVES * RPW)   // 1,331,200 buckets

typedef __bf16 bf16;
typedef __bf16 bf16x8 __attribute__((ext_vector_type(8)));
typedef __bf16 bf16x4 __attribute__((ext_vector_type(4)));
typedef float floatx4 __attribute__((ext_vector_type(4)));

// ---------------- cast fp32 -> bf16 (4 elems / thread) ----------------
__global__ void cast_kernel(const float* __restrict__ in, bf16* __restrict__ out, int n4) {
    int i = blockIdx.x * blockDim.x + threadIdx.x;
    if (i >= n4) return;
    float4 v = reinterpret_cast<const float4*>(in)[i];
    bf16x4 o;
    o[0] = (bf16)v.x; o[1] = (bf16)v.y; o[2] = (bf16)v.z; o[3] = (bf16)v.w;
    reinterpret_cast<bf16x4*>(out)[i] = o;
}

// ---------------- bucketed CSR build ----------------
// key = (t*4096 + w)*13 + k  with w = r & 4095, k = r >> 12, t = col >> 11.
// => a wave's 13 buckets at tile t are CONTIGUOUS: bounds row_start[base..base+13]
//    and the 13 edge segments form one contiguous superseg in ecv.
__global__ void hist_kernel(const int* __restrict__ rows, const int* __restrict__ cols,
                            int* __restrict__ cnt, int E) {
    int i = blockIdx.x * blockDim.x + threadIdx.x;
    if (i < E) {
        int r = rows[i];
        int key = ((cols[i] >> 11) * 4096 + (r & 4095)) * 13 + (r >> 12);
        atomicAdd(&cnt[key], 1);
    }
}

// hierarchical scan over NB2 buckets
__global__ __launch_bounds__(1024) void scanA_kernel(const int* __restrict__ cnt,
                                                     int* __restrict__ row_start,
                                                     int* __restrict__ blksum, int n) {
    __shared__ int s[1024];
    const int t = threadIdx.x;
    int i = blockIdx.x * 1024 + t;
    int v = (i < n) ? cnt[i] : 0;
    s[t] = v;
    __syncthreads();
    for (int off = 1; off < 1024; off <<= 1) {
        int u = (t >= off) ? s[t - off] : 0;
        __syncthreads();
        s[t] += u;
        __syncthreads();
    }
    if (i < n) row_start[i] = s[t] - v;  // exclusive within block
    if (t == 1023) blksum[blockIdx.x] = s[1023];
}

__global__ __launch_bounds__(1024) void scanB_kernel(const int* __restrict__ blksum,
                                                     int* __restrict__ blkoff, int nb) {
    __shared__ int s[1024];
    const int t = threadIdx.x;
    const int base = t * 2;
    int a = (base < nb) ? blksum[base] : 0;
    int b = (base + 1 < nb) ? blksum[base + 1] : 0;
    s[t] = a + b;
    __syncthreads();
    for (int off = 1; off < 1024; off <<= 1) {
        int u = (t >= off) ? s[t - off] : 0;
        __syncthreads();
        s[t] += u;
        __syncthreads();
    }
    int excl = (t == 0) ? 0 : s[t - 1];
    if (base < nb) blkoff[base] = excl;
    if (base + 1 < nb) blkoff[base + 1] = excl + a;
}

__global__ __launch_bounds__(1024) void scanC_kernel(int* __restrict__ row_start,
                                                     const int* __restrict__ blkoff,
                                                     int* __restrict__ cursor, int n) {
    int i = blockIdx.x * 1024 + threadIdx.x;
    if (i >= n) return;
    int v = row_start[i] + blkoff[i >> 10];
    row_start[i] = v;
    cursor[i] = v;
    if (i == n - 1) row_start[n] = N_EDGES;
}

__global__ void scatter_kernel(const int* __restrict__ rows, const int* __restrict__ cols,
                               const float* __restrict__ vals, int* __restrict__ cursor,
                               int2* __restrict__ ecv, int E) {
    int i = blockIdx.x * blockDim.x + threadIdx.x;
    if (i >= E) return;
    int r = rows[i];
    int c = cols[i];
    int key = ((c >> 11) * 4096 + (r & 4095)) * 13 + (r >> 12);
    int p = atomicAdd(&cursor[key], 1);
    ecv[p] = make_int2(c, __float_as_int(vals[i]));  // plain col; k is static in spmm
}

// ---------------- GEMM: y[M][512] = xb[M][512] @ Wb[512][512]^T (bf16 in, bf16 out) ----
__global__ __launch_bounds__(256) void gemm_kernel(const bf16* __restrict__ A,
                                                   const bf16* __restrict__ B,
                                                   bf16* __restrict__ C) {
    __shared__ bf16 lA[128 * 32];
    __shared__ bf16 lB[128 * 32];
    const int t = threadIdx.x;
    const int wave = t >> 6;
    const int lane = t & 63;
    const int rowBase = blockIdx.x * 128;
    const int colBase = blockIdx.y * 128;
    const int wm = (wave >> 1) * 64;
    const int wn = (wave & 1) * 64;
    floatx4 acc[4][4] = {};

    const int r_a = t >> 2;       // 0..63 (tile row, first half)
    const int kk = (t & 3) * 8;   // k offset within 32-chunk

    const int l15 = lane & 15;
    const int koff = (lane >> 4) * 8;

    for (int k0 = 0; k0 < DIM; k0 += 32) {
#pragma unroll
        for (int j = 0; j < 2; j++) {
            int row = rowBase + r_a + j * 64;
            if (row > N_NODES - 1) row = N_NODES - 1;  // clamp OOB loads (stores guarded)
            const bf16* g = A + (size_t)row * DIM + k0 + kk;
            bf16* l = lA + wave * 512 + j * 2048;  // wave-uniform base; HW adds lane*16B
            __builtin_amdgcn_global_load_lds(
                (const __attribute__((address_space(1))) void*)g,
                (__attribute__((address_space(3))) void*)l, 16, 0, 0);
        }
#pragma unroll
        for (int j = 0; j < 2; j++) {
            int row = colBase + r_a + j * 64;  // always < 512
            const bf16* g = B + (size_t)row * DIM + k0 + kk;
            bf16* l = lB + wave * 512 + j * 2048;
            __builtin_amdgcn_global_load_lds(
                (const __attribute__((address_space(1))) void*)g,
                (__attribute__((address_space(3))) void*)l, 16, 0, 0);
        }
        __syncthreads();
        bf16x8 af[4], bfr[4];
#pragma unroll
        for (int i = 0; i < 4; i++)
            af[i] = *reinterpret_cast<const bf16x8*>(lA + (wm + i * 16 + l15) * 32 + koff);
#pragma unroll
        for (int j = 0; j < 4; j++)
            bfr[j] = *reinterpret_cast<const bf16x8*>(lB + (wn + j * 16 + l15) * 32 + koff);
#pragma unroll
        for (int i = 0; i < 4; i++)
#pragma unroll
            for (int j = 0; j < 4; j++)
                acc[i][j] = __builtin_amdgcn_mfma_f32_16x16x32_bf16(af[i], bfr[j], acc[i][j], 0, 0, 0);
        __syncthreads();
    }
    // epilogue: D row = (lane>>4)*4+reg (m), col = lane&15 (n)
    const int rquad = (lane >> 4) * 4;
#pragma unroll
    for (int i = 0; i < 4; i++) {
#pragma unroll
        for (int reg = 0; reg < 4; reg++) {
            int gr = rowBase + wm + i * 16 + rquad + reg;
            if (gr >= N_NODES) continue;
#pragma unroll
            for (int j = 0; j < 4; j++) {
                int gc = colBase + wn + j * 16 + l15;
                C[(size_t)gr * DIM + gc] = (bf16)acc[i][j][reg];
            }
        }
    }
}

// ---------------- SpMM v7: co-resident sweep + superseg bounds + STATIC k ----------------
// v6 lesson (rule #20): the 13-way switch on readfirstlane(k) was if-converted back to
// dynamic register indexing -> acc spilled to scratch -> 50 GB RMW traffic. v7 keeps k
// as an UNROLLED loop index (structurally static, v5-proven AGPR-clean) and instead
// removes v5's per-bucket latency chains using the superseg layout:
//   per tile: 14 contiguous bounds -> 1 load wave; first-edge descriptors of all 13
//   buckets prefetched (addresses known) -> 1 load wave; first-edge gather addresses
//   then all ready, so the compiler can run several buckets' gathers in flight.
// Only 2nd+ edges of a bucket (Poisson 1.28: ~44% of edges) still chain.
__device__ __forceinline__ float blo(uint32_t w) { return __uint_as_float(w << 16); }
__device__ __forceinline__ float bhi(uint32_t w) { return __uint_as_float(w & 0xffff0000u); }

__device__ __forceinline__ void fmac8(float* acc, float v, const uint4& w) {
    acc[0] += v * blo(w.x); acc[1] += v * bhi(w.x);
    acc[2] += v * blo(w.y); acc[3] += v * bhi(w.y);
    acc[4] += v * blo(w.z); acc[5] += v * bhi(w.z);
    acc[6] += v * blo(w.w); acc[7] += v * bhi(w.w);
}

__device__ __forceinline__ uint4 grow(const uint32_t* yb, int col, int laneo) {
    return *reinterpret_cast<const uint4*>(yb + (size_t)col * 256 + laneo);
}

__global__ __launch_bounds__(256, 3) void spmm_kernel(const int* __restrict__ row_start,
                                                      const int2* __restrict__ ecv,
                                                      const bf16* __restrict__ y,
                                                      float* __restrict__ y2) {
    const int wid = (blockIdx.x << 2) + (threadIdx.x >> 6);  // 0..4095
    const int lane = threadIdx.x & 63;
    const uint32_t* yb = reinterpret_cast<const uint32_t*>(y);
    const int laneo = lane * 4;  // uint32 offset within a 1KB y-row

    float acc[RPW][8];
#pragma unroll
    for (int k = 0; k < RPW; k++)
#pragma unroll
        for (int j = 0; j < 8; j++) acc[k][j] = 0.f;

    for (int t = 0; t < NT; t++) {
        const int base = (t * SWEEP_WAVES + wid) * RPW;
        // all 14 bounds: independent loads, one latency (v5 paid this per bucket)
        int b[RPW + 1];
#pragma unroll
        for (int k = 0; k <= RPW; k++) b[k] = row_start[base + k];
        // prefetch first-edge descriptor of every bucket (clamped addr if empty)
        int2 d[RPW];
#pragma unroll
        for (int k = 0; k < RPW; k++) d[k] = ecv[(b[k] < b[k + 1]) ? b[k] : 0];
        // static-k consume: acc index is the unroll constant -> AGPR-clean
#pragma unroll
        for (int k = 0; k < RPW; k++) {
            int i = b[k];
            const int e = b[k + 1];
            if (i < e) {
                uint4 w0 = grow(yb, d[k].x, laneo);
                fmac8(acc[k], __int_as_float(d[k].y), w0);
                for (i++; i < e; i++) {
                    int2 ed = ecv[i];
                    uint4 w2 = grow(yb, ed.x, laneo);
                    fmac8(acc[k], __int_as_float(ed.y), w2);
                }
            }
        }
    }

#pragma unroll
    for (int k = 0; k < RPW; k++) {
        const int r = wid + (k << 12);
        if (r < N_NODES) {
            float4* out = reinterpret_cast<float4*>(y2 + (size_t)r * DIM + lane * 8);
            out[0] = make_float4(acc[k][0], acc[k][1], acc[k][2], acc[k][3]);
            out[1] = make_float4(acc[k][4], acc[k][5], acc[k][6], acc[k][7]);
        }
    }
}

// ---------------- reduction: colsum[512] + total sum of squares ----------------
#define RED_GRID 512
__global__ __launch_bounds__(256) void reduce_kernel(const float* __restrict__ y2,
                                                     float* __restrict__ colsum,
                                                     float* __restrict__ totsq) {
    const int t = threadIdx.x;
    const int d2 = t * 2;
    float c0 = 0.f, c1 = 0.f, sq = 0.f;
    for (int r = blockIdx.x; r < N_NODES; r += RED_GRID * 2) {
        float2 v = *reinterpret_cast<const float2*>(y2 + (size_t)r * DIM + d2);
        int r2 = r + RED_GRID;
        float2 u = (r2 < N_NODES)
                       ? *reinterpret_cast<const float2*>(y2 + (size_t)r2 * DIM + d2)
                       : make_float2(0.f, 0.f);
        c0 += v.x + u.x;
        c1 += v.y + u.y;
        sq += v.x * v.x + v.y * v.y + u.x * u.x + u.y * u.y;
    }
    atomicAdd(&colsum[d2], c0);
    atomicAdd(&colsum[d2 + 1], c1);
    __shared__ float ssq[256];
    ssq[t] = sq;
    __syncthreads();
    for (int off = 128; off > 0; off >>= 1) {
        if (t < off) ssq[t] += ssq[t + off];
        __syncthreads();
    }
    if (t == 0) atomicAdd(totsq, ssq[0]);
}

__global__ void scalar_kernel(const float* __restrict__ colsum, const float* __restrict__ totsq,
                              const float* __restrict__ scale, float* __restrict__ sfac) {
    __shared__ float sm[512];
    const int t = threadIdx.x;
    float mu = colsum[t] * (1.0f / N_NODES);
    sm[t] = mu * mu;
    __syncthreads();
    for (int off = 256; off > 0; off >>= 1) {
        if (t < off) sm[t] += sm[t + off];
        __syncthreads();
    }
    if (t == 0) {
        float var = totsq[0] * (1.0f / N_NODES) - sm[0];
        sfac[0] = rsqrtf(var) * (1.0f + scale[0]) * sqrtf((float)DIM);
    }
}

// ---------------- final: out = relu((y2 - mu) * s) + x  (in place on d_out) ----------------
__global__ void final_kernel(float* __restrict__ y2, const float* __restrict__ x,
                             const float* __restrict__ colsum, const float* __restrict__ sfac,
                             int n4) {
    int i = blockIdx.x * blockDim.x + threadIdx.x;
    if (i >= n4) return;
    const float invN = 1.0f / N_NODES;
    float4 v = reinterpret_cast<float4*>(y2)[i];
    float4 xv = reinterpret_cast<const float4*>(x)[i];
    float4 mu = reinterpret_cast<const float4*>(colsum)[i & 127];
    float s = sfac[0];
    v.x = fmaxf((v.x - mu.x * invN) * s, 0.0f) + xv.x;
    v.y = fmaxf((v.y - mu.y * invN) * s, 0.0f) + xv.y;
    v.z = fmaxf((v.z - mu.z * invN) * s, 0.0f) + xv.z;
    v.w = fmaxf((v.w - mu.w * invN) * s, 0.0f) + xv.w;
    reinterpret_cast<float4*>(y2)[i] = v;
}

extern "C" void kernel_launch(void* const* d_in, const int* in_sizes, int n_in,
                              void* d_out, int out_size, void* d_ws, size_t ws_size,
                              hipStream_t stream) {
    const float* x        = (const float*)d_in[0];
    const int*   adj_rows = (const int*)d_in[1];
    const int*   adj_cols = (const int*)d_in[2];
    const float* adj_vals = (const float*)d_in[3];
    const float* weight   = (const float*)d_in[4];
    const float* scale    = (const float*)d_in[5];
    float* out = (float*)d_out;  // doubles as y2 buffer

    char* ws = (char*)d_ws;
    size_t off = 0;
    auto alloc = [&](size_t b) {
        char* p = ws + off;
        off += (b + 255) & ~(size_t)255;
        return p;
    };
    const int nblk = (NB2 + 1023) / 1024;  // 1300
    bf16*  xb        = (bf16*)alloc((size_t)N_NODES * DIM * 2);   // 51.2 MB
    int2*  ecv       = (int2*)xb;  // ALIAS: gemm (reader of xb) completes before scatter writes
    bf16*  Wb        = (bf16*)alloc((size_t)DIM * DIM * 2);       // 0.5 MB
    bf16*  y         = (bf16*)alloc((size_t)N_NODES * DIM * 2);   // 51.2 MB
    int*   cnt       = (int*)alloc((size_t)NB2 * 4);              // 5.3 MB
    int*   cursor    = cnt;        // ALIAS: cnt dead after scanA; cursor born in scanC
    int*   row_start = (int*)alloc((size_t)(NB2 + 32) * 4);       // 5.3 MB (+pad)
    int*   blksum    = (int*)alloc((size_t)nblk * 4);
    int*   blkoff    = (int*)alloc((size_t)nblk * 4);
    float* colsum    = (float*)alloc(512 * 4);
    float* totsq     = (float*)alloc(4);
    float* sfac      = (float*)alloc(4);
    (void)ws_size; (void)in_sizes; (void)n_in; (void)out_size;

    hipMemsetAsync(cnt, 0, (size_t)NB2 * 4, stream);
    hipMemsetAsync(colsum, 0, 512 * 4, stream);
    hipMemsetAsync(totsq, 0, 4, stream);

    const int n4x = N_NODES * DIM / 4;  // 6,400,000
    const int n4w = DIM * DIM / 4;      // 65,536
    cast_kernel<<<(n4x + 255) / 256, 256, 0, stream>>>(x, xb, n4x);
    cast_kernel<<<(n4w + 255) / 256, 256, 0, stream>>>(weight, Wb, n4w);

    // GEMM first: frees xb so ecv can alias it
    gemm_kernel<<<dim3((N_NODES + 127) / 128, DIM / 128), 256, 0, stream>>>(xb, Wb, y);

    hist_kernel<<<(N_EDGES + 255) / 256, 256, 0, stream>>>(adj_rows, adj_cols, cnt, N_EDGES);
    scanA_kernel<<<nblk, 1024, 0, stream>>>(cnt, row_start, blksum, NB2);
    scanB_kernel<<<1, 1024, 0, stream>>>(blksum, blkoff, nblk);
    scanC_kernel<<<nblk, 1024, 0, stream>>>(row_start, blkoff, cursor, NB2);
    scatter_kernel<<<(N_EDGES + 255) / 256, 256, 0, stream>>>(adj_rows, adj_cols, adj_vals,
                                                              cursor, ecv, N_EDGES);

    // persistent tile-synchronized sweep
    spmm_kernel<<<1024, 256, 0, stream>>>(row_start, ecv, y, out);

    reduce_kernel<<<RED_GRID, 256, 0, stream>>>(out, colsum, totsq);
    scalar_kernel<<<1, 512, 0, stream>>>(colsum, totsq, scale, sfac);
    final_kernel<<<(n4x + 255) / 256, 256, 0, stream>>>(out, x, colsum, sfac, n4x);
}

// Round 9
// 738.729 us; speedup vs baseline: 13.5211x; 1.2386x over previous
//
#include <hip/hip_runtime.h>
#include <hip/hip_bf16.h>
#include <cstdint>
#include <cstddef>

#define N_NODES 50000
#define DIM 512
#define N_EDGES 1600000
#define NT 25           // column tiles of 2048 nodes (2 MB of bf16 y per tile)
#define NB (N_NODES * NT)
#define GPANELS 391     // ceil(50000/128) row panels in gemm

typedef __bf16 bf16;
typedef __bf16 bf16x8 __attribute__((ext_vector_type(8)));
typedef __bf16 bf16x4 __attribute__((ext_vector_type(4)));
typedef float floatx4 __attribute__((ext_vector_type(4)));

// ---------------- cast fp32 -> bf16 (4 elems / thread) ----------------
__global__ void cast_kernel(const float* __restrict__ in, bf16* __restrict__ out, int n4) {
    int i = blockIdx.x * blockDim.x + threadIdx.x;
    if (i >= n4) return;
    float4 v = reinterpret_cast<const float4*>(in)[i];
    bf16x4 o;
    o[0] = (bf16)v.x; o[1] = (bf16)v.y; o[2] = (bf16)v.z; o[3] = (bf16)v.w;
    reinterpret_cast<bf16x4*>(out)[i] = o;
}

// ---------------- bucketed CSR build: key = row*NT + (col>>11) ----------------
__global__ void hist_kernel(const int* __restrict__ rows, const int* __restrict__ cols,
                            int* __restrict__ cnt, int E) {
    int i = blockIdx.x * blockDim.x + threadIdx.x;
    if (i < E) {
        int key = rows[i] * NT + (cols[i] >> 11);
        atomicAdd(&cnt[key], 1);
    }
}

// hierarchical scan over NB buckets
__global__ __launch_bounds__(1024) void scanA_kernel(const int* __restrict__ cnt,
                                                     int* __restrict__ row_start,
                                                     int* __restrict__ blksum, int n) {
    __shared__ int s[1024];
    const int t = threadIdx.x;
    int i = blockIdx.x * 1024 + t;
    int v = (i < n) ? cnt[i] : 0;
    s[t] = v;
    __syncthreads();
    for (int off = 1; off < 1024; off <<= 1) {
        int u = (t >= off) ? s[t - off] : 0;
        __syncthreads();
        s[t] += u;
        __syncthreads();
    }
    if (i < n) row_start[i] = s[t] - v;  // exclusive within block
    if (t == 1023) blksum[blockIdx.x] = s[1023];
}

__global__ __launch_bounds__(1024) void scanB_kernel(const int* __restrict__ blksum,
                                                     int* __restrict__ blkoff, int nb) {
    __shared__ int s[1024];
    const int t = threadIdx.x;
    const int base = t * 2;
    int a = (base < nb) ? blksum[base] : 0;
    int b = (base + 1 < nb) ? blksum[base + 1] : 0;
    s[t] = a + b;
    __syncthreads();
    for (int off = 1; off < 1024; off <<= 1) {
        int u = (t >= off) ? s[t - off] : 0;
        __syncthreads();
        s[t] += u;
        __syncthreads();
    }
    int excl = (t == 0) ? 0 : s[t - 1];
    if (base < nb) blkoff[base] = excl;
    if (base + 1 < nb) blkoff[base + 1] = excl + a;
}

__global__ __launch_bounds__(1024) void scanC_kernel(int* __restrict__ row_start,
                                                     const int* __restrict__ blkoff,
                                                     int* __restrict__ cursor, int n) {
    int i = blockIdx.x * 1024 + threadIdx.x;
    if (i >= n) return;
    int v = row_start[i] + blkoff[i >> 10];
    row_start[i] = v;
    cursor[i] = v;
    if (i == n - 1) row_start[n] = N_EDGES;
}

__global__ void scatter_kernel(const int* __restrict__ rows, const int* __restrict__ cols,
                               const float* __restrict__ vals, int* __restrict__ cursor,
                               int2* __restrict__ ecv, int E) {
    int i = blockIdx.x * blockDim.x + threadIdx.x;
    if (i >= E) return;
    int c = cols[i];
    int key = rows[i] * NT + (c >> 11);
    int p = atomicAdd(&cursor[key], 1);
    ecv[p] = make_int2(c, __float_as_int(vals[i]));
}

// ---------------- GEMM: y[M][512] = xb[M][512] @ Wb[512][512]^T (bf16 in, bf16 out) ----
// v8: 1D grid with XCD-chunked swizzle so the 4 col-tiles of one 128-row A-panel
// dispatch to the SAME XCD (d mod 8 == panel mod 8) and run near-concurrently ->
// the panel is fetched into that XCD's L2 ~once instead of 4 XCDs fetching it
// independently. A traffic ~205 MB -> ~51 MB.
__global__ __launch_bounds__(256) void gemm_kernel(const bf16* __restrict__ A,
                                                   const bf16* __restrict__ B,
                                                   bf16* __restrict__ C) {
    __shared__ bf16 lA[128 * 32];
    __shared__ bf16 lB[128 * 32];
    const int d = blockIdx.x;
    const int p = (d & 7) + ((d >> 5) << 3);  // row panel
    const int c = (d >> 3) & 3;               // col tile
    if (p >= GPANELS) return;
    const int t = threadIdx.x;
    const int wave = t >> 6;
    const int lane = t & 63;
    const int rowBase = p * 128;
    const int colBase = c * 128;
    const int wm = (wave >> 1) * 64;
    const int wn = (wave & 1) * 64;
    floatx4 acc[4][4] = {};

    const int r_a = t >> 2;       // 0..63 (tile row, first half)
    const int kk = (t & 3) * 8;   // k offset within 32-chunk

    const int l15 = lane & 15;
    const int koff = (lane >> 4) * 8;

    for (int k0 = 0; k0 < DIM; k0 += 32) {
#pragma unroll
        for (int j = 0; j < 2; j++) {
            int row = rowBase + r_a + j * 64;
            if (row > N_NODES - 1) row = N_NODES - 1;  // clamp OOB loads (stores guarded)
            const bf16* g = A + (size_t)row * DIM + k0 + kk;
            bf16* l = lA + wave * 512 + j * 2048;  // wave-uniform base; HW adds lane*16B
            __builtin_amdgcn_global_load_lds(
                (const __attribute__((address_space(1))) void*)g,
                (__attribute__((address_space(3))) void*)l, 16, 0, 0);
        }
#pragma unroll
        for (int j = 0; j < 2; j++) {
            int row = colBase + r_a + j * 64;  // always < 512
            const bf16* g = B + (size_t)row * DIM + k0 + kk;
            bf16* l = lB + wave * 512 + j * 2048;
            __builtin_amdgcn_global_load_lds(
                (const __attribute__((address_space(1))) void*)g,
                (__attribute__((address_space(3))) void*)l, 16, 0, 0);
        }
        __syncthreads();
        bf16x8 af[4], bfr[4];
#pragma unroll
        for (int i = 0; i < 4; i++)
            af[i] = *reinterpret_cast<const bf16x8*>(lA + (wm + i * 16 + l15) * 32 + koff);
#pragma unroll
        for (int j = 0; j < 4; j++)
            bfr[j] = *reinterpret_cast<const bf16x8*>(lB + (wn + j * 16 + l15) * 32 + koff);
#pragma unroll
        for (int i = 0; i < 4; i++)
#pragma unroll
            for (int j = 0; j < 4; j++)
                acc[i][j] = __builtin_amdgcn_mfma_f32_16x16x32_bf16(af[i], bfr[j], acc[i][j], 0, 0, 0);
        __syncthreads();
    }
    // epilogue: D row = (lane>>4)*4+reg (m), col = lane&15 (n)
    const int rquad = (lane >> 4) * 4;
#pragma unroll
    for (int i = 0; i < 4; i++) {
#pragma unroll
        for (int reg = 0; reg < 4; reg++) {
            int gr = rowBase + wm + i * 16 + rquad + reg;
            if (gr >= N_NODES) continue;
#pragma unroll
            for (int j = 0; j < 4; j++) {
                int gc = colBase + wn + j * 16 + l15;
                C[(size_t)gr * DIM + gc] = (bf16)acc[i][j][reg];
            }
        }
    }
}

// ---------------- SpMM (v1, measured best 227us): one wave per row, lane owns 8 dims,
// edges tile-sorted; free-running grid = 12500 blocks. The co-resident tile-sweep
// branch (v5-v7) cut FETCH to 440 MB but throttled service 4->1.4 TB/s: net loss.
__device__ __forceinline__ float blo(uint32_t w) { return __uint_as_float(w << 16); }
__device__ __forceinline__ float bhi(uint32_t w) { return __uint_as_float(w & 0xffff0000u); }

__device__ __forceinline__ void fmac8(float* acc, float v, const uint4& w) {
    acc[0] += v * blo(w.x); acc[1] += v * bhi(w.x);
    acc[2] += v * blo(w.y); acc[3] += v * bhi(w.y);
    acc[4] += v * blo(w.z); acc[5] += v * bhi(w.z);
    acc[6] += v * blo(w.w); acc[7] += v * bhi(w.w);
}

__global__ __launch_bounds__(256) void spmm_kernel(const int* __restrict__ row_start,
                                                   const int2* __restrict__ ecv,
                                                   const bf16* __restrict__ y,
                                                   float* __restrict__ y2) {
    const int wave = threadIdx.x >> 6;
    const int lane = threadIdx.x & 63;
    const int r = blockIdx.x * 4 + wave;  // grid = 12500 exactly -> r < 50000
    const int s = row_start[r * NT];
    const int e = row_start[(r + 1) * NT];
    float acc[8] = {0.f, 0.f, 0.f, 0.f, 0.f, 0.f, 0.f, 0.f};
    const uint32_t* yb = reinterpret_cast<const uint32_t*>(y);

    int i = s;
    for (; i + 3 < e; i += 4) {
        int2 e0 = ecv[i], e1 = ecv[i + 1], e2 = ecv[i + 2], e3 = ecv[i + 3];
        uint4 w0 = *reinterpret_cast<const uint4*>(yb + (size_t)e0.x * 256 + lane * 4);
        uint4 w1 = *reinterpret_cast<const uint4*>(yb + (size_t)e1.x * 256 + lane * 4);
        uint4 w2 = *reinterpret_cast<const uint4*>(yb + (size_t)e2.x * 256 + lane * 4);
        uint4 w3 = *reinterpret_cast<const uint4*>(yb + (size_t)e3.x * 256 + lane * 4);
        fmac8(acc, __int_as_float(e0.y), w0);
        fmac8(acc, __int_as_float(e1.y), w1);
        fmac8(acc, __int_as_float(e2.y), w2);
        fmac8(acc, __int_as_float(e3.y), w3);
    }
    for (; i < e; i++) {
        int2 e0 = ecv[i];
        uint4 w0 = *reinterpret_cast<const uint4*>(yb + (size_t)e0.x * 256 + lane * 4);
        fmac8(acc, __int_as_float(e0.y), w0);
    }
    float4* out = reinterpret_cast<float4*>(y2 + (size_t)r * DIM + lane * 8);
    out[0] = make_float4(acc[0], acc[1], acc[2], acc[3]);
    out[1] = make_float4(acc[4], acc[5], acc[6], acc[7]);
}

// ---------------- reduction: colsum[512] + total sum of squares ----------------
// 512 blocks (2 blocks/CU) + 2-row unroll for ILP (R1 delta suggests ~30us saved vs 256).
#define RED_GRID 512
__global__ __launch_bounds__(256) void reduce_kernel(const float* __restrict__ y2,
                                                     float* __restrict__ colsum,
                                                     float* __restrict__ totsq) {
    const int t = threadIdx.x;
    const int d2 = t * 2;
    float c0 = 0.f, c1 = 0.f, sq = 0.f;
    for (int r = blockIdx.x; r < N_NODES; r += RED_GRID * 2) {
        float2 v = *reinterpret_cast<const float2*>(y2 + (size_t)r * DIM + d2);
        int r2 = r + RED_GRID;
        float2 u = (r2 < N_NODES)
                       ? *reinterpret_cast<const float2*>(y2 + (size_t)r2 * DIM + d2)
                       : make_float2(0.f, 0.f);
        c0 += v.x + u.x;
        c1 += v.y + u.y;
        sq += v.x * v.x + v.y * v.y + u.x * u.x + u.y * u.y;
    }
    atomicAdd(&colsum[d2], c0);
    atomicAdd(&colsum[d2 + 1], c1);
    __shared__ float ssq[256];
    ssq[t] = sq;
    __syncthreads();
    for (int off = 128; off > 0; off >>= 1) {
        if (t < off) ssq[t] += ssq[t + off];
        __syncthreads();
    }
    if (t == 0) atomicAdd(totsq, ssq[0]);
}

__global__ void scalar_kernel(const float* __restrict__ colsum, const float* __restrict__ totsq,
                              const float* __restrict__ scale, float* __restrict__ sfac) {
    __shared__ float sm[512];
    const int t = threadIdx.x;
    float mu = colsum[t] * (1.0f / N_NODES);
    sm[t] = mu * mu;
    __syncthreads();
    for (int off = 256; off > 0; off >>= 1) {
        if (t < off) sm[t] += sm[t + off];
        __syncthreads();
    }
    if (t == 0) {
        float var = totsq[0] * (1.0f / N_NODES) - sm[0];
        sfac[0] = rsqrtf(var) * (1.0f + scale[0]) * sqrtf((float)DIM);
    }
}

// ---------------- final: out = relu((y2 - mu) * s) + x  (in place on d_out) ----------------
__global__ void final_kernel(float* __restrict__ y2, const float* __restrict__ x,
                             const float* __restrict__ colsum, const float* __restrict__ sfac,
                             int n4) {
    int i = blockIdx.x * blockDim.x + threadIdx.x;
    if (i >= n4) return;
    const float invN = 1.0f / N_NODES;
    float4 v = reinterpret_cast<float4*>(y2)[i];
    float4 xv = reinterpret_cast<const float4*>(x)[i];
    float4 mu = reinterpret_cast<const float4*>(colsum)[i & 127];
    float s = sfac[0];
    v.x = fmaxf((v.x - mu.x * invN) * s, 0.0f) + xv.x;
    v.y = fmaxf((v.y - mu.y * invN) * s, 0.0f) + xv.y;
    v.z = fmaxf((v.z - mu.z * invN) * s, 0.0f) + xv.z;
    v.w = fmaxf((v.w - mu.w * invN) * s, 0.0f) + xv.w;
    reinterpret_cast<float4*>(y2)[i] = v;
}

extern "C" void kernel_launch(void* const* d_in, const int* in_sizes, int n_in,
                              void* d_out, int out_size, void* d_ws, size_t ws_size,
                              hipStream_t stream) {
    const float* x        = (const float*)d_in[0];
    const int*   adj_rows = (const int*)d_in[1];
    const int*   adj_cols = (const int*)d_in[2];
    const float* adj_vals = (const float*)d_in[3];
    const float* weight   = (const float*)d_in[4];
    const float* scale    = (const float*)d_in[5];
    float* out = (float*)d_out;  // doubles as y2 buffer

    char* ws = (char*)d_ws;
    size_t off = 0;
    auto alloc = [&](size_t b) {
        char* p = ws + off;
        off += (b + 255) & ~(size_t)255;
        return p;
    };
    const int nblk = (NB + 1023) / 1024;  // 1221
    bf16*  xb        = (bf16*)alloc((size_t)N_NODES * DIM * 2);   // 51.2 MB
    int2*  ecv       = (int2*)xb;  // ALIAS: gemm (reader of xb) completes before scatter writes
    bf16*  Wb        = (bf16*)alloc((size_t)DIM * DIM * 2);       // 0.5 MB
    bf16*  y         = (bf16*)alloc((size_t)N_NODES * DIM * 2);   // 51.2 MB
    int*   cnt       = (int*)alloc((size_t)NB * 4);               // 5 MB
    int*   cursor    = cnt;        // ALIAS: cnt dead after scanA; cursor born in scanC
    int*   row_start = (int*)alloc((size_t)(NB + 1) * 4);         // 5 MB
    int*   blksum    = (int*)alloc((size_t)nblk * 4);
    int*   blkoff    = (int*)alloc((size_t)nblk * 4);
    float* colsum    = (float*)alloc(512 * 4);
    float* totsq     = (float*)alloc(4);
    float* sfac      = (float*)alloc(4);
    (void)ws_size; (void)in_sizes; (void)n_in; (void)out_size;

    hipMemsetAsync(cnt, 0, (size_t)NB * 4, stream);
    hipMemsetAsync(colsum, 0, 512 * 4, stream);
    hipMemsetAsync(totsq, 0, 4, stream);

    const int n4x = N_NODES * DIM / 4;  // 6,400,000
    const int n4w = DIM * DIM / 4;      // 65,536
    cast_kernel<<<(n4x + 255) / 256, 256, 0, stream>>>(x, xb, n4x);
    cast_kernel<<<(n4w + 255) / 256, 256, 0, stream>>>(weight, Wb, n4w);

    // GEMM first: frees xb so ecv can alias it.
    // 1568 = 49 XCD-chunks * 32; decode (p,c) inside; 4 idle blocks guarded.
    gemm_kernel<<<1568, 256, 0, stream>>>(xb, Wb, y);

    hist_kernel<<<(N_EDGES + 255) / 256, 256, 0, stream>>>(adj_rows, adj_cols, cnt, N_EDGES);
    scanA_kernel<<<nblk, 1024, 0, stream>>>(cnt, row_start, blksum, NB);
    scanB_kernel<<<1, 1024, 0, stream>>>(blksum, blkoff, nblk);
    scanC_kernel<<<nblk, 1024, 0, stream>>>(row_start, blkoff, cursor, NB);
    scatter_kernel<<<(N_EDGES + 255) / 256, 256, 0, stream>>>(adj_rows, adj_cols, adj_vals,
                                                              cursor, ecv, N_EDGES);

    spmm_kernel<<<N_NODES / 4, 256, 0, stream>>>(row_start, ecv, y, out);

    reduce_kernel<<<RED_GRID, 256, 0, stream>>>(out, colsum, totsq);
    scalar_kernel<<<1, 512, 0, stream>>>(colsum, totsq, scale, sfac);
    final_kernel<<<(n4x + 255) / 256, 256, 0, stream>>>(out, x, colsum, sfac, n4x);
}

// Round 10
// 684.920 us; speedup vs baseline: 14.5834x; 1.0786x over previous
//
#include <hip/hip_runtime.h>
#include <hip/hip_bf16.h>
#include <cstdint>
#include <cstddef>

#define N_NODES 50000
#define DIM 512
#define N_EDGES 1600000
#define NT 25           // column tiles of 2048 nodes (2 MB of bf16 y per tile)
#define NB (N_NODES * NT)
#define GPANELS 391     // ceil(50000/128) row panels in gemm
#define NSHAD 8         // shadow copies for reduce atomics

typedef __bf16 bf16;
typedef __bf16 bf16x8 __attribute__((ext_vector_type(8)));
typedef __bf16 bf16x4 __attribute__((ext_vector_type(4)));
typedef float floatx4 __attribute__((ext_vector_type(4)));

// ---------------- cast fp32 -> bf16 (4 elems / thread) ----------------
__global__ void cast_kernel(const float* __restrict__ in, bf16* __restrict__ out, int n4) {
    int i = blockIdx.x * blockDim.x + threadIdx.x;
    if (i >= n4) return;
    float4 v = reinterpret_cast<const float4*>(in)[i];
    bf16x4 o;
    o[0] = (bf16)v.x; o[1] = (bf16)v.y; o[2] = (bf16)v.z; o[3] = (bf16)v.w;
    reinterpret_cast<bf16x4*>(out)[i] = o;
}

// ---------------- bucketed CSR build: key = row*NT + (col>>11) ----------------
__global__ void hist_kernel(const int* __restrict__ rows, const int* __restrict__ cols,
                            int* __restrict__ cnt, int E) {
    int i = blockIdx.x * blockDim.x + threadIdx.x;
    if (i < E) {
        int key = rows[i] * NT + (cols[i] >> 11);
        atomicAdd(&cnt[key], 1);
    }
}

// scanA v10: wave-shuffle scan (6 shfl steps + wave-sum scan), 2 barriers
// instead of the 20-barrier LDS ladder.
__global__ __launch_bounds__(1024) void scanA_kernel(const int* __restrict__ cnt,
                                                     int* __restrict__ row_start,
                                                     int* __restrict__ blksum, int n) {
    const int t = threadIdx.x;
    int i = blockIdx.x * 1024 + t;
    int v = (i < n) ? cnt[i] : 0;
    // inclusive scan within each 64-lane wave
    int s = v;
#pragma unroll
    for (int off = 1; off < 64; off <<= 1) {
        int u = __shfl_up(s, off, 64);
        if ((t & 63) >= off) s += u;
    }
    __shared__ int wsum[16];
    if ((t & 63) == 63) wsum[t >> 6] = s;
    __syncthreads();
    if (t < 16) {
        int w = wsum[t];
#pragma unroll
        for (int off = 1; off < 16; off <<= 1) {
            int u = __shfl_up(w, off, 16);
            if (t >= off) w += u;
        }
        wsum[t] = w;  // inclusive scan of wave sums
    }
    __syncthreads();
    int base = (t >= 64) ? wsum[(t >> 6) - 1] : 0;
    int incl = s + base;
    if (i < n) row_start[i] = incl - v;  // exclusive within block
    if (t == 1023) blksum[blockIdx.x] = incl;
}

__global__ __launch_bounds__(1024) void scanB_kernel(const int* __restrict__ blksum,
                                                     int* __restrict__ blkoff, int nb) {
    __shared__ int s[1024];
    const int t = threadIdx.x;
    const int base = t * 2;
    int a = (base < nb) ? blksum[base] : 0;
    int b = (base + 1 < nb) ? blksum[base + 1] : 0;
    s[t] = a + b;
    __syncthreads();
    for (int off = 1; off < 1024; off <<= 1) {
        int u = (t >= off) ? s[t - off] : 0;
        __syncthreads();
        s[t] += u;
        __syncthreads();
    }
    int excl = (t == 0) ? 0 : s[t - 1];
    if (base < nb) blkoff[base] = excl;
    if (base + 1 < nb) blkoff[base + 1] = excl + a;
}

__global__ __launch_bounds__(1024) void scanC_kernel(int* __restrict__ row_start,
                                                     const int* __restrict__ blkoff,
                                                     int* __restrict__ cursor, int n) {
    int i = blockIdx.x * 1024 + threadIdx.x;
    if (i >= n) return;
    int v = row_start[i] + blkoff[i >> 10];
    row_start[i] = v;
    cursor[i] = v;
    if (i == n - 1) row_start[n] = N_EDGES;
}

__global__ void scatter_kernel(const int* __restrict__ rows, const int* __restrict__ cols,
                               const float* __restrict__ vals, int* __restrict__ cursor,
                               int2* __restrict__ ecv, int E) {
    int i = blockIdx.x * blockDim.x + threadIdx.x;
    if (i >= E) return;
    int c = cols[i];
    int key = rows[i] * NT + (c >> 11);
    int p = atomicAdd(&cursor[key], 1);
    ecv[p] = make_int2(c, __float_as_int(vals[i]));
}

// ---------------- GEMM: y[M][512] = xb[M][512] @ Wb[512][512]^T (bf16 in, bf16 out) ----
// 1D grid with XCD-chunked swizzle (neutral vs 2D in R9 A/B; kept, harmless).
__global__ __launch_bounds__(256) void gemm_kernel(const bf16* __restrict__ A,
                                                   const bf16* __restrict__ B,
                                                   bf16* __restrict__ C) {
    __shared__ bf16 lA[128 * 32];
    __shared__ bf16 lB[128 * 32];
    const int d = blockIdx.x;
    const int p = (d & 7) + ((d >> 5) << 3);  // row panel
    const int c = (d >> 3) & 3;               // col tile
    if (p >= GPANELS) return;
    const int t = threadIdx.x;
    const int wave = t >> 6;
    const int lane = t & 63;
    const int rowBase = p * 128;
    const int colBase = c * 128;
    const int wm = (wave >> 1) * 64;
    const int wn = (wave & 1) * 64;
    floatx4 acc[4][4] = {};

    const int r_a = t >> 2;       // 0..63 (tile row, first half)
    const int kk = (t & 3) * 8;   // k offset within 32-chunk

    const int l15 = lane & 15;
    const int koff = (lane >> 4) * 8;

    for (int k0 = 0; k0 < DIM; k0 += 32) {
#pragma unroll
        for (int j = 0; j < 2; j++) {
            int row = rowBase + r_a + j * 64;
            if (row > N_NODES - 1) row = N_NODES - 1;  // clamp OOB loads (stores guarded)
            const bf16* g = A + (size_t)row * DIM + k0 + kk;
            bf16* l = lA + wave * 512 + j * 2048;  // wave-uniform base; HW adds lane*16B
            __builtin_amdgcn_global_load_lds(
                (const __attribute__((address_space(1))) void*)g,
                (__attribute__((address_space(3))) void*)l, 16, 0, 0);
        }
#pragma unroll
        for (int j = 0; j < 2; j++) {
            int row = colBase + r_a + j * 64;  // always < 512
            const bf16* g = B + (size_t)row * DIM + k0 + kk;
            bf16* l = lB + wave * 512 + j * 2048;
            __builtin_amdgcn_global_load_lds(
                (const __attribute__((address_space(1))) void*)g,
                (__attribute__((address_space(3))) void*)l, 16, 0, 0);
        }
        __syncthreads();
        bf16x8 af[4], bfr[4];
#pragma unroll
        for (int i = 0; i < 4; i++)
            af[i] = *reinterpret_cast<const bf16x8*>(lA + (wm + i * 16 + l15) * 32 + koff);
#pragma unroll
        for (int j = 0; j < 4; j++)
            bfr[j] = *reinterpret_cast<const bf16x8*>(lB + (wn + j * 16 + l15) * 32 + koff);
#pragma unroll
        for (int i = 0; i < 4; i++)
#pragma unroll
            for (int j = 0; j < 4; j++)
                acc[i][j] = __builtin_amdgcn_mfma_f32_16x16x32_bf16(af[i], bfr[j], acc[i][j], 0, 0, 0);
        __syncthreads();
    }
    // epilogue: D row = (lane>>4)*4+reg (m), col = lane&15 (n)
    const int rquad = (lane >> 4) * 4;
#pragma unroll
    for (int i = 0; i < 4; i++) {
#pragma unroll
        for (int reg = 0; reg < 4; reg++) {
            int gr = rowBase + wm + i * 16 + rquad + reg;
            if (gr >= N_NODES) continue;
#pragma unroll
            for (int j = 0; j < 4; j++) {
                int gc = colBase + wn + j * 16 + l15;
                C[(size_t)gr * DIM + gc] = (bf16)acc[i][j][reg];
            }
        }
    }
}

// ---------------- SpMM (v1, measured best ~228us) ----------------
__device__ __forceinline__ float blo(uint32_t w) { return __uint_as_float(w << 16); }
__device__ __forceinline__ float bhi(uint32_t w) { return __uint_as_float(w & 0xffff0000u); }

__device__ __forceinline__ void fmac8(float* acc, float v, const uint4& w) {
    acc[0] += v * blo(w.x); acc[1] += v * bhi(w.x);
    acc[2] += v * blo(w.y); acc[3] += v * bhi(w.y);
    acc[4] += v * blo(w.z); acc[5] += v * bhi(w.z);
    acc[6] += v * blo(w.w); acc[7] += v * bhi(w.w);
}

__global__ __launch_bounds__(256) void spmm_kernel(const int* __restrict__ row_start,
                                                   const int2* __restrict__ ecv,
                                                   const bf16* __restrict__ y,
                                                   float* __restrict__ y2) {
    const int wave = threadIdx.x >> 6;
    const int lane = threadIdx.x & 63;
    const int r = blockIdx.x * 4 + wave;  // grid = 12500 exactly -> r < 50000
    const int s = row_start[r * NT];
    const int e = row_start[(r + 1) * NT];
    float acc[8] = {0.f, 0.f, 0.f, 0.f, 0.f, 0.f, 0.f, 0.f};
    const uint32_t* yb = reinterpret_cast<const uint32_t*>(y);

    int i = s;
    for (; i + 3 < e; i += 4) {
        int2 e0 = ecv[i], e1 = ecv[i + 1], e2 = ecv[i + 2], e3 = ecv[i + 3];
        uint4 w0 = *reinterpret_cast<const uint4*>(yb + (size_t)e0.x * 256 + lane * 4);
        uint4 w1 = *reinterpret_cast<const uint4*>(yb + (size_t)e1.x * 256 + lane * 4);
        uint4 w2 = *reinterpret_cast<const uint4*>(yb + (size_t)e2.x * 256 + lane * 4);
        uint4 w3 = *reinterpret_cast<const uint4*>(yb + (size_t)e3.x * 256 + lane * 4);
        fmac8(acc, __int_as_float(e0.y), w0);
        fmac8(acc, __int_as_float(e1.y), w1);
        fmac8(acc, __int_as_float(e2.y), w2);
        fmac8(acc, __int_as_float(e3.y), w3);
    }
    for (; i < e; i++) {
        int2 e0 = ecv[i];
        uint4 w0 = *reinterpret_cast<const uint4*>(yb + (size_t)e0.x * 256 + lane * 4);
        fmac8(acc, __int_as_float(e0.y), w0);
    }
    float4* out = reinterpret_cast<float4*>(y2 + (size_t)r * DIM + lane * 8);
    out[0] = make_float4(acc[0], acc[1], acc[2], acc[3]);
    out[1] = make_float4(acc[4], acc[5], acc[6], acc[7]);
}

// ---------------- reduction v10: colsum[512] + total sum of squares ----------------
// R3/R4 subtraction shows the old reduce cost ~100us for a 100MB read (1 TB/s):
// only 2 float2 loads in flight/thread -> latency-starved. v10: contiguous 16-row
// chunks, 16 independent loads in flight (32 VGPR), ~16MB outstanding grid-wide.
// Atomics insurance: 8 shadow copies (blockIdx&7) so colsum RMWs spread 8x.
#define RED_GRID 512
#define RED_CHUNK 16
__global__ __launch_bounds__(256) void reduce_kernel(const float* __restrict__ y2,
                                                     float* __restrict__ colsumS,
                                                     float* __restrict__ totsqS) {
    const int t = threadIdx.x;
    const int d2 = t * 2;
    float c0 = 0.f, c1 = 0.f, sq = 0.f;
    for (int r0 = blockIdx.x * RED_CHUNK; r0 < N_NODES; r0 += RED_GRID * RED_CHUNK) {
        float2 v[RED_CHUNK];
#pragma unroll
        for (int j = 0; j < RED_CHUNK; j++) {
            int r = r0 + j;
            v[j] = (r < N_NODES)
                       ? *reinterpret_cast<const float2*>(y2 + (size_t)r * DIM + d2)
                       : make_float2(0.f, 0.f);
        }
#pragma unroll
        for (int j = 0; j < RED_CHUNK; j++) {
            c0 += v[j].x;
            c1 += v[j].y;
            sq += v[j].x * v[j].x + v[j].y * v[j].y;
        }
    }
    const int sh = blockIdx.x & (NSHAD - 1);
    atomicAdd(&colsumS[sh * DIM + d2], c0);
    atomicAdd(&colsumS[sh * DIM + d2 + 1], c1);
    __shared__ float ssq[256];
    ssq[t] = sq;
    __syncthreads();
    for (int off = 128; off > 0; off >>= 1) {
        if (t < off) ssq[t] += ssq[t + off];
        __syncthreads();
    }
    if (t == 0) atomicAdd(&totsqS[sh], ssq[0]);
}

__global__ void scalar_kernel(const float* __restrict__ colsumS, const float* __restrict__ totsqS,
                              const float* __restrict__ scale, float* __restrict__ sfac,
                              float* __restrict__ colsum) {
    __shared__ float sm[512];
    const int t = threadIdx.x;
    float s = 0.f;
#pragma unroll
    for (int c = 0; c < NSHAD; c++) s += colsumS[c * DIM + t];
    colsum[t] = s;
    float mu = s * (1.0f / N_NODES);
    sm[t] = mu * mu;
    __syncthreads();
    for (int off = 256; off > 0; off >>= 1) {
        if (t < off) sm[t] += sm[t + off];
        __syncthreads();
    }
    if (t == 0) {
        float tq = 0.f;
#pragma unroll
        for (int c = 0; c < NSHAD; c++) tq += totsqS[c];
        float var = tq * (1.0f / N_NODES) - sm[0];
        sfac[0] = rsqrtf(var) * (1.0f + scale[0]) * sqrtf((float)DIM);
    }
}

// ---------------- final: out = relu((y2 - mu) * s) + x  (in place on d_out) ----------------
__global__ void final_kernel(float* __restrict__ y2, const float* __restrict__ x,
                             const float* __restrict__ colsum, const float* __restrict__ sfac,
                             int n4) {
    int i = blockIdx.x * blockDim.x + threadIdx.x;
    if (i >= n4) return;
    const float invN = 1.0f / N_NODES;
    float4 v = reinterpret_cast<float4*>(y2)[i];
    float4 xv = reinterpret_cast<const float4*>(x)[i];
    float4 mu = reinterpret_cast<const float4*>(colsum)[i & 127];
    float s = sfac[0];
    v.x = fmaxf((v.x - mu.x * invN) * s, 0.0f) + xv.x;
    v.y = fmaxf((v.y - mu.y * invN) * s, 0.0f) + xv.y;
    v.z = fmaxf((v.z - mu.z * invN) * s, 0.0f) + xv.z;
    v.w = fmaxf((v.w - mu.w * invN) * s, 0.0f) + xv.w;
    reinterpret_cast<float4*>(y2)[i] = v;
}

extern "C" void kernel_launch(void* const* d_in, const int* in_sizes, int n_in,
                              void* d_out, int out_size, void* d_ws, size_t ws_size,
                              hipStream_t stream) {
    const float* x        = (const float*)d_in[0];
    const int*   adj_rows = (const int*)d_in[1];
    const int*   adj_cols = (const int*)d_in[2];
    const float* adj_vals = (const float*)d_in[3];
    const float* weight   = (const float*)d_in[4];
    const float* scale    = (const float*)d_in[5];
    float* out = (float*)d_out;  // doubles as y2 buffer

    char* ws = (char*)d_ws;
    size_t off = 0;
    auto alloc = [&](size_t b) {
        char* p = ws + off;
        off += (b + 255) & ~(size_t)255;
        return p;
    };
    const int nblk = (NB + 1023) / 1024;  // 1221
    bf16*  xb        = (bf16*)alloc((size_t)N_NODES * DIM * 2);   // 51.2 MB
    int2*  ecv       = (int2*)xb;  // ALIAS: gemm (reader of xb) completes before scatter writes
    bf16*  Wb        = (bf16*)alloc((size_t)DIM * DIM * 2);       // 0.5 MB
    bf16*  y         = (bf16*)alloc((size_t)N_NODES * DIM * 2);   // 51.2 MB
    int*   cnt       = (int*)alloc((size_t)NB * 4);               // 5 MB
    int*   cursor    = cnt;        // ALIAS: cnt dead after scanA; cursor born in scanC
    int*   row_start = (int*)alloc((size_t)(NB + 1) * 4);         // 5 MB
    int*   blksum    = (int*)alloc((size_t)nblk * 4);
    int*   blkoff    = (int*)alloc((size_t)nblk * 4);
    float* colsumS   = (float*)alloc((size_t)NSHAD * DIM * 4);    // 16 KB
    float* totsqS    = (float*)alloc((size_t)NSHAD * 4);
    float* colsum    = (float*)alloc(512 * 4);
    float* sfac      = (float*)alloc(4);
    (void)ws_size; (void)in_sizes; (void)n_in; (void)out_size;

    hipMemsetAsync(cnt, 0, (size_t)NB * 4, stream);
    hipMemsetAsync(colsumS, 0, (size_t)NSHAD * DIM * 4 + 256, stream);  // covers totsqS too

    const int n4x = N_NODES * DIM / 4;  // 6,400,000
    const int n4w = DIM * DIM / 4;      // 65,536
    cast_kernel<<<(n4x + 255) / 256, 256, 0, stream>>>(x, xb, n4x);
    cast_kernel<<<(n4w + 255) / 256, 256, 0, stream>>>(weight, Wb, n4w);

    // GEMM first: frees xb so ecv can alias it.
    gemm_kernel<<<1568, 256, 0, stream>>>(xb, Wb, y);

    hist_kernel<<<(N_EDGES + 255) / 256, 256, 0, stream>>>(adj_rows, adj_cols, cnt, N_EDGES);
    scanA_kernel<<<nblk, 1024, 0, stream>>>(cnt, row_start, blksum, NB);
    scanB_kernel<<<1, 1024, 0, stream>>>(blksum, blkoff, nblk);
    scanC_kernel<<<nblk, 1024, 0, stream>>>(row_start, blkoff, cursor, NB);
    scatter_kernel<<<(N_EDGES + 255) / 256, 256, 0, stream>>>(adj_rows, adj_cols, adj_vals,
                                                              cursor, ecv, N_EDGES);

    spmm_kernel<<<N_NODES / 4, 256, 0, stream>>>(row_start, ecv, y, out);

    reduce_kernel<<<RED_GRID, 256, 0, stream>>>(out, colsumS, totsqS);
    scalar_kernel<<<1, 512, 0, stream>>>(colsumS, totsqS, scale, sfac, colsum);
    final_kernel<<<(n4x + 255) / 256, 256, 0, stream>>>(out, x, colsum, sfac, n4x);
}